// Round 1
// baseline (1052.508 us; speedup 1.0000x reference)
//
#include <hip/hip_runtime.h>
#include <math.h>

// Problem constants (fixed by setup_inputs)
#define BB 8
#define TT 8
#define NN 196
#define DD 768
#define HH 12
#define HD 64
#define TN (TT * NN)   // 1568
#define MM (BB * TN)   // 12544
#define D3 (3 * DD)    // 2304

// ---------------------------------------------------------------------------
// fp32 tiled GEMM: C[M x Ncol] = A[M x K] @ B[K x Ncol] (+ optional bias)
// Requirements: M % 128 == 0, Ncol % 128 == 0, K % 16 == 0 (all hold here).
// 128x128 block tile, BK=16, 256 threads, 8x8 register micro-tile.
// ---------------------------------------------------------------------------
__global__ __launch_bounds__(256) void gemm_f32(
    const float* __restrict__ A, const float* __restrict__ Bm,
    float* __restrict__ C, int K, int Ncol, const float* __restrict__ bias) {
  __shared__ float As[16][132];  // transposed A tile, padded to dodge bank conflicts
  __shared__ float Bs[16][128];

  const int tid = threadIdx.x;
  const int tx = tid & 15;   // column group (8 cols each)
  const int ty = tid >> 4;   // row group (8 rows each)
  const int bm = blockIdx.y * 128;
  const int bn = blockIdx.x * 128;

  // A-tile load mapping: 128 rows x 16 k = 512 float4; 2 per thread (same row)
  const int a_row = tid >> 1;          // 0..127
  const int a_k4  = (tid & 1) * 2;     // float4 index within row: 0 or 2
  // B-tile load mapping: 16 rows x 32 float4; 2 per thread (rows r and r+8)
  const int b_row = tid >> 5;          // 0..7
  const int b_c4  = tid & 31;          // 0..31

  float acc[8][8];
#pragma unroll
  for (int i = 0; i < 8; i++)
#pragma unroll
    for (int j = 0; j < 8; j++) acc[i][j] = 0.0f;

  for (int kt = 0; kt < K; kt += 16) {
    // global loads
    const float4* asrc = (const float4*)(A + (size_t)(bm + a_row) * K + kt);
    float4 a0 = asrc[a_k4];
    float4 a1 = asrc[a_k4 + 1];
    const float4* bsrc0 = (const float4*)(Bm + (size_t)(kt + b_row) * Ncol + bn);
    float4 b0 = bsrc0[b_c4];
    const float4* bsrc1 = (const float4*)(Bm + (size_t)(kt + b_row + 8) * Ncol + bn);
    float4 b1 = bsrc1[b_c4];

    __syncthreads();  // previous tile fully consumed before overwrite

    // store A transposed: As[k][m]
    As[a_k4 * 4 + 0][a_row] = a0.x;
    As[a_k4 * 4 + 1][a_row] = a0.y;
    As[a_k4 * 4 + 2][a_row] = a0.z;
    As[a_k4 * 4 + 3][a_row] = a0.w;
    As[(a_k4 + 1) * 4 + 0][a_row] = a1.x;
    As[(a_k4 + 1) * 4 + 1][a_row] = a1.y;
    As[(a_k4 + 1) * 4 + 2][a_row] = a1.z;
    As[(a_k4 + 1) * 4 + 3][a_row] = a1.w;
    ((float4*)&Bs[b_row][0])[b_c4] = b0;
    ((float4*)&Bs[b_row + 8][0])[b_c4] = b1;

    __syncthreads();

#pragma unroll
    for (int k = 0; k < 16; k++) {
      float4 af0 = *(const float4*)&As[k][ty * 8];
      float4 af1 = *(const float4*)&As[k][ty * 8 + 4];
      float4 bf0 = *(const float4*)&Bs[k][tx * 8];
      float4 bf1 = *(const float4*)&Bs[k][tx * 8 + 4];
      float a[8] = {af0.x, af0.y, af0.z, af0.w, af1.x, af1.y, af1.z, af1.w};
      float b[8] = {bf0.x, bf0.y, bf0.z, bf0.w, bf1.x, bf1.y, bf1.z, bf1.w};
#pragma unroll
      for (int i = 0; i < 8; i++)
#pragma unroll
        for (int j = 0; j < 8; j++) acc[i][j] = fmaf(a[i], b[j], acc[i][j]);
    }
  }

  float bvals[8];
#pragma unroll
  for (int j = 0; j < 8; j++) bvals[j] = 0.0f;
  if (bias != nullptr) {
#pragma unroll
    for (int j = 0; j < 8; j++) bvals[j] = bias[bn + tx * 8 + j];
  }

#pragma unroll
  for (int i = 0; i < 8; i++) {
    float* crow = C + (size_t)(bm + ty * 8 + i) * Ncol + bn + tx * 8;
    float4 c0, c1;
    c0.x = acc[i][0] + bvals[0];
    c0.y = acc[i][1] + bvals[1];
    c0.z = acc[i][2] + bvals[2];
    c0.w = acc[i][3] + bvals[3];
    c1.x = acc[i][4] + bvals[4];
    c1.y = acc[i][5] + bvals[5];
    c1.z = acc[i][6] + bvals[6];
    c1.w = acc[i][7] + bvals[7];
    ((float4*)crow)[0] = c0;
    ((float4*)crow)[1] = c1;
  }
}

// ---------------------------------------------------------------------------
// Spatial attention per (b,h,t) + temporal mean of V folded in.
// One block per frame-head; one Q-row per thread (196 active of 256).
// K/V staged in LDS in two 98-row tiles; online softmax across tiles.
// out layout: row = b*TN + t*NN + n, col = h*HD + d  (ready for proj GEMM)
// ---------------------------------------------------------------------------
#define TILE_J 98

__global__ __launch_bounds__(256) void attn_kernel(
    const float* __restrict__ qkv, float* __restrict__ out) {
  __shared__ float Ks[TILE_J * HD];
  __shared__ float Vs[TILE_J * HD];
  __shared__ float red[256];
  __shared__ float vmean[HD];

  const int bi = blockIdx.x;            // b*H*T + h*T + t
  const int t = bi % TT;
  const int h = (bi / TT) % HH;
  const int b = bi / (TT * HH);

  const float* base = qkv + (size_t)(b * TN + t * NN) * D3 + h * HD;

  const int tid = threadIdx.x;
  const int n = tid;                    // Q row handled by this thread
  const int d = tid & 63;
  const int quarter = tid >> 6;

  // Load my Q row into registers
  float q[HD];
  if (n < NN) {
    const float4* gq = (const float4*)(base + (size_t)n * D3);
#pragma unroll
    for (int i = 0; i < 16; i++) {
      float4 f = gq[i];
      q[4 * i + 0] = f.x;
      q[4 * i + 1] = f.y;
      q[4 * i + 2] = f.z;
      q[4 * i + 3] = f.w;
    }
  }

  const float scale = 0.125f;  // 64^-0.5
  float m = -3.0e38f, l = 0.0f;
  float o[HD];
#pragma unroll
  for (int i = 0; i < HD; i++) o[i] = 0.0f;
  float vpart = 0.0f;

  for (int tile = 0; tile < 2; tile++) {
    const int j0 = tile * TILE_J;
    __syncthreads();  // previous tile fully consumed
    // stage K,V rows [j0, j0+98): 98*16 = 1568 float4 per matrix
    for (int idx = tid; idx < TILE_J * 16; idx += 256) {
      int row = idx >> 4;
      int c4 = idx & 15;
      const float4* gk =
          (const float4*)(base + (size_t)(j0 + row) * D3 + DD) + c4;
      ((float4*)Ks)[row * 16 + c4] = *gk;
      const float4* gv =
          (const float4*)(base + (size_t)(j0 + row) * D3 + 2 * DD) + c4;
      ((float4*)Vs)[row * 16 + c4] = *gv;
    }
    __syncthreads();

    // v-mean partials (all 256 threads)
    for (int r = quarter; r < TILE_J; r += 4) vpart += Vs[r * HD + d];

    // online-softmax attention over this tile's keys
    if (n < NN) {
      for (int jj = 0; jj < TILE_J; jj++) {
        const float4* kr = (const float4*)(Ks + jj * HD);
        float s0 = 0.0f, s1 = 0.0f, s2 = 0.0f, s3 = 0.0f;
#pragma unroll
        for (int i = 0; i < 16; i++) {
          float4 f = kr[i];
          s0 = fmaf(q[4 * i + 0], f.x, s0);
          s1 = fmaf(q[4 * i + 1], f.y, s1);
          s2 = fmaf(q[4 * i + 2], f.z, s2);
          s3 = fmaf(q[4 * i + 3], f.w, s3);
        }
        float s = ((s0 + s1) + (s2 + s3)) * scale;
        float p;
        if (s > m) {
          float alpha = __expf(m - s);  // first iter: exp(-huge) -> 0
          l *= alpha;
#pragma unroll
          for (int i = 0; i < HD; i++) o[i] *= alpha;
          m = s;
          p = 1.0f;
        } else {
          p = __expf(s - m);
        }
        l += p;
        const float4* vr = (const float4*)(Vs + jj * HD);
#pragma unroll
        for (int i = 0; i < 16; i++) {
          float4 f = vr[i];
          o[4 * i + 0] = fmaf(p, f.x, o[4 * i + 0]);
          o[4 * i + 1] = fmaf(p, f.y, o[4 * i + 1]);
          o[4 * i + 2] = fmaf(p, f.z, o[4 * i + 2]);
          o[4 * i + 3] = fmaf(p, f.w, o[4 * i + 3]);
        }
      }
    }
  }

  // finalize v-mean
  red[tid] = vpart;
  __syncthreads();
  if (tid < 64) {
    vmean[d] = (red[d] + red[64 + d] + red[128 + d] + red[192 + d]) *
               (1.0f / (float)NN);
  }
  __syncthreads();

  if (n < NN) {
    float inv = 1.0f / l;
    float* orow = out + (size_t)(b * TN + t * NN + n) * DD + h * HD;
#pragma unroll
    for (int i = 0; i < 16; i++) {
      float4 r;
      r.x = fmaf(o[4 * i + 0], inv, vmean[4 * i + 0]);
      r.y = fmaf(o[4 * i + 1], inv, vmean[4 * i + 1]);
      r.z = fmaf(o[4 * i + 2], inv, vmean[4 * i + 2]);
      r.w = fmaf(o[4 * i + 3], inv, vmean[4 * i + 3]);
      ((float4*)orow)[i] = r;
    }
  }
}

// ---------------------------------------------------------------------------
extern "C" void kernel_launch(void* const* d_in, const int* in_sizes, int n_in,
                              void* d_out, int out_size, void* d_ws,
                              size_t ws_size, hipStream_t stream) {
  (void)in_sizes;
  (void)n_in;
  (void)out_size;
  (void)ws_size;
  const float* x      = (const float*)d_in[0];
  // d_in[1] = T, d_in[2] = N (fixed, hard-coded)
  const float* w_qkv  = (const float*)d_in[3];
  const float* w_proj = (const float*)d_in[4];
  const float* b_proj = (const float*)d_in[5];
  float* out = (float*)d_out;

  float* qkv  = (float*)d_ws;                      // MM x D3
  float* attn = qkv + (size_t)MM * D3;             // MM x DD

  // 1) qkv = x @ w_qkv
  gemm_f32<<<dim3(D3 / 128, MM / 128), 256, 0, stream>>>(x, w_qkv, qkv, DD, D3,
                                                         nullptr);
  // 2) spatial attention + temporal mean
  attn_kernel<<<BB * HH * TT, 256, 0, stream>>>(qkv, attn);
  // 3) out = attn @ w_proj + b_proj
  gemm_f32<<<dim3(DD / 128, MM / 128), 256, 0, stream>>>(attn, w_proj, out, DD,
                                                         DD, b_proj);
}

// Round 2
// 480.270 us; speedup vs baseline: 2.1915x; 2.1915x over previous
//
#include <hip/hip_runtime.h>
#include <math.h>

// Problem constants (fixed by setup_inputs)
#define BB 8
#define TT 8
#define NN 196
#define DD 768
#define HH 12
#define HD 64
#define TN (TT * TT * 0 + TT * NN)  // 1568
#define MM (BB * TN)                // 12544
#define D3 (3 * DD)                 // 2304

typedef _Float16 f16;
typedef _Float16 f16x8 __attribute__((ext_vector_type(8)));
typedef _Float16 f16x4 __attribute__((ext_vector_type(4)));
typedef float f32x4 __attribute__((ext_vector_type(4)));
typedef unsigned int u32;

// async global->LDS, 16B per lane; LDS dest must be wave-uniform base + lane*16
#define GLDS16(gp, lp)                                                        \
  __builtin_amdgcn_global_load_lds(                                           \
      (const __attribute__((address_space(1))) u32*)(gp),                     \
      (__attribute__((address_space(3))) u32*)(lp), 16, 0, 0)

// ---------------------------------------------------------------------------
// fp16 NT GEMM via MFMA: C[M][Ncol] = A[M][K] @ Bt[Ncol][K]^T (+bias), fp32 out
// 128x128 block tile, BK=32, 256 threads (4 waves in 2x2), 4x4 of 16x16x32.
// M%128==0, Ncol%128==0, K%32==0 required (all hold here).
// ---------------------------------------------------------------------------
__global__ __launch_bounds__(256) void gemm_f16nt(
    const f16* __restrict__ A, const f16* __restrict__ Bt,
    float* __restrict__ C, int K, int Ncol, const float* __restrict__ bias) {
  __shared__ f16 As[128 * 32];
  __shared__ f16 Bs[128 * 32];

  const int tid = threadIdx.x;
  const int lane = tid & 63;
  const int wave = tid >> 6;
  const int wy = wave >> 1, wx = wave & 1;
  const int bm = blockIdx.y * 128;
  const int bn = blockIdx.x * 128;

  // staging: 512 chunks of 8 halves (16B) per matrix; 2 chunks/thread each
  const int ci0 = tid;        // chunk = row*4 + col8
  const int ci1 = tid + 256;
  const int r0 = ci0 >> 2, c0 = ci0 & 3;
  const int r1 = ci1 >> 2, c1 = ci1 & 3;

  const f16* a0p = A + (size_t)(bm + r0) * K + c0 * 8;
  const f16* a1p = A + (size_t)(bm + r1) * K + c1 * 8;
  const f16* b0p = Bt + (size_t)(bn + r0) * K + c0 * 8;
  const f16* b1p = Bt + (size_t)(bn + r1) * K + c1 * 8;

  f32x4 acc[4][4];
#pragma unroll
  for (int i = 0; i < 4; i++)
#pragma unroll
    for (int j = 0; j < 4; j++) acc[i][j] = (f32x4)0.0f;

  // fragment LDS offsets (halves): row*32 + quad*8
  const int fr = lane & 15;          // row within 16-tile
  const int fq = (lane >> 4) * 8;    // k offset

  for (int kt = 0; kt < K; kt += 32) {
    GLDS16(a0p + kt, &As[ci0 * 8]);
    GLDS16(a1p + kt, &As[ci1 * 8]);
    GLDS16(b0p + kt, &Bs[ci0 * 8]);
    GLDS16(b1p + kt, &Bs[ci1 * 8]);
    __syncthreads();

    f16x8 af[4], bf[4];
#pragma unroll
    for (int mi = 0; mi < 4; mi++)
      af[mi] = *(const f16x8*)&As[(wy * 64 + mi * 16 + fr) * 32 + fq];
#pragma unroll
    for (int ni = 0; ni < 4; ni++)
      bf[ni] = *(const f16x8*)&Bs[(wx * 64 + ni * 16 + fr) * 32 + fq];

#pragma unroll
    for (int mi = 0; mi < 4; mi++)
#pragma unroll
      for (int ni = 0; ni < 4; ni++)
        acc[mi][ni] = __builtin_amdgcn_mfma_f32_16x16x32_f16(
            af[mi], bf[ni], acc[mi][ni], 0, 0, 0);

    __syncthreads();
  }

  // epilogue: C/D layout col=lane&15, row=(lane>>4)*4+reg
#pragma unroll
  for (int mi = 0; mi < 4; mi++) {
    const int row0 = bm + wy * 64 + mi * 16 + (lane >> 4) * 4;
#pragma unroll
    for (int ni = 0; ni < 4; ni++) {
      const int col = bn + wx * 64 + ni * 16 + (lane & 15);
      float bv = (bias != nullptr) ? bias[col] : 0.0f;
#pragma unroll
      for (int r = 0; r < 4; r++)
        C[(size_t)(row0 + r) * Ncol + col] = acc[mi][ni][r] + bv;
    }
  }
}

// ---------------------------------------------------------------------------
// elementwise fp32 -> fp16 (vectorized x4)
// ---------------------------------------------------------------------------
__global__ __launch_bounds__(256) void conv_f32_to_f16(
    const float* __restrict__ in, f16* __restrict__ out, int n4) {
  int i = blockIdx.x * blockDim.x + threadIdx.x;
  const int stride = gridDim.x * blockDim.x;
  for (; i < n4; i += stride) {
    float4 f = ((const float4*)in)[i];
    f16x4 h;
    h[0] = (f16)f.x;
    h[1] = (f16)f.y;
    h[2] = (f16)f.z;
    h[3] = (f16)f.w;
    ((f16x4*)out)[i] = h;
  }
}

// ---------------------------------------------------------------------------
// W[K][Ncol] fp32 -> Wt[Ncol][K] fp16 (32x32 LDS tile transpose)
// ---------------------------------------------------------------------------
__global__ __launch_bounds__(256) void transpose_f32_to_f16(
    const float* __restrict__ W, f16* __restrict__ Wt, int K, int Ncol) {
  __shared__ float tileS[32][33];
  const int k0 = blockIdx.y * 32, n0 = blockIdx.x * 32;
  const int tx = threadIdx.x & 31, ty = threadIdx.x >> 5;  // ty 0..7
#pragma unroll
  for (int i = 0; i < 4; i++)
    tileS[ty + i * 8][tx] = W[(size_t)(k0 + ty + i * 8) * Ncol + n0 + tx];
  __syncthreads();
#pragma unroll
  for (int i = 0; i < 4; i++)
    Wt[(size_t)(n0 + ty + i * 8) * K + k0 + tx] = (f16)tileS[tx][ty + i * 8];
}

// ---------------------------------------------------------------------------
// Spatial attention per (b,h,t) + temporal mean of V folded in.
// Reads fp32 qkv; writes fp16 attn output (row = b*TN+t*NN+n, col = h*HD+d).
// ---------------------------------------------------------------------------
#define TILE_J 98

__global__ __launch_bounds__(256) void attn_kernel(
    const float* __restrict__ qkv, f16* __restrict__ out) {
  __shared__ float Ks[TILE_J * HD];
  __shared__ float Vs[TILE_J * HD];
  __shared__ float red[256];
  __shared__ float vmean[HD];

  const int bi = blockIdx.x;  // b*H*T + h*T + t
  const int t = bi % TT;
  const int h = (bi / TT) % HH;
  const int b = bi / (TT * HH);

  const float* base = qkv + (size_t)(b * TN + t * NN) * D3 + h * HD;

  const int tid = threadIdx.x;
  const int n = tid;
  const int d = tid & 63;
  const int quarter = tid >> 6;

  float q[HD];
  if (n < NN) {
    const float4* gq = (const float4*)(base + (size_t)n * D3);
#pragma unroll
    for (int i = 0; i < 16; i++) {
      float4 f = gq[i];
      q[4 * i + 0] = f.x;
      q[4 * i + 1] = f.y;
      q[4 * i + 2] = f.z;
      q[4 * i + 3] = f.w;
    }
  }

  const float scale = 0.125f;
  float m = -3.0e38f, l = 0.0f;
  float o[HD];
#pragma unroll
  for (int i = 0; i < HD; i++) o[i] = 0.0f;
  float vpart = 0.0f;

  for (int tile = 0; tile < 2; tile++) {
    const int j0 = tile * TILE_J;
    __syncthreads();
    for (int idx = tid; idx < TILE_J * 16; idx += 256) {
      int row = idx >> 4;
      int c4 = idx & 15;
      const float4* gk =
          (const float4*)(base + (size_t)(j0 + row) * D3 + DD) + c4;
      ((float4*)Ks)[row * 16 + c4] = *gk;
      const float4* gv =
          (const float4*)(base + (size_t)(j0 + row) * D3 + 2 * DD) + c4;
      ((float4*)Vs)[row * 16 + c4] = *gv;
    }
    __syncthreads();

    for (int r = quarter; r < TILE_J; r += 4) vpart += Vs[r * HD + d];

    if (n < NN) {
      for (int jj = 0; jj < TILE_J; jj++) {
        const float4* kr = (const float4*)(Ks + jj * HD);
        float s0 = 0.0f, s1 = 0.0f, s2 = 0.0f, s3 = 0.0f;
#pragma unroll
        for (int i = 0; i < 16; i++) {
          float4 f = kr[i];
          s0 = fmaf(q[4 * i + 0], f.x, s0);
          s1 = fmaf(q[4 * i + 1], f.y, s1);
          s2 = fmaf(q[4 * i + 2], f.z, s2);
          s3 = fmaf(q[4 * i + 3], f.w, s3);
        }
        float s = ((s0 + s1) + (s2 + s3)) * scale;
        float p;
        if (s > m) {
          float alpha = __expf(m - s);
          l *= alpha;
#pragma unroll
          for (int i = 0; i < HD; i++) o[i] *= alpha;
          m = s;
          p = 1.0f;
        } else {
          p = __expf(s - m);
        }
        l += p;
        const float4* vr = (const float4*)(Vs + jj * HD);
#pragma unroll
        for (int i = 0; i < 16; i++) {
          float4 f = vr[i];
          o[4 * i + 0] = fmaf(p, f.x, o[4 * i + 0]);
          o[4 * i + 1] = fmaf(p, f.y, o[4 * i + 1]);
          o[4 * i + 2] = fmaf(p, f.z, o[4 * i + 2]);
          o[4 * i + 3] = fmaf(p, f.w, o[4 * i + 3]);
        }
      }
    }
  }

  red[tid] = vpart;
  __syncthreads();
  if (tid < 64) {
    vmean[d] = (red[d] + red[64 + d] + red[128 + d] + red[192 + d]) *
               (1.0f / (float)NN);
  }
  __syncthreads();

  if (n < NN) {
    float inv = 1.0f / l;
    f16* orow = out + (size_t)(b * TN + t * NN + n) * DD + h * HD;
#pragma unroll
    for (int i = 0; i < 16; i++) {
      f16x4 r;
      r[0] = (f16)fmaf(o[4 * i + 0], inv, vmean[4 * i + 0]);
      r[1] = (f16)fmaf(o[4 * i + 1], inv, vmean[4 * i + 1]);
      r[2] = (f16)fmaf(o[4 * i + 2], inv, vmean[4 * i + 2]);
      r[3] = (f16)fmaf(o[4 * i + 3], inv, vmean[4 * i + 3]);
      *(f16x4*)(orow + 4 * i) = r;
    }
  }
}

// ---------------------------------------------------------------------------
extern "C" void kernel_launch(void* const* d_in, const int* in_sizes, int n_in,
                              void* d_out, int out_size, void* d_ws,
                              size_t ws_size, hipStream_t stream) {
  (void)in_sizes;
  (void)n_in;
  (void)out_size;
  (void)ws_size;
  const float* x      = (const float*)d_in[0];
  // d_in[1] = T, d_in[2] = N (fixed, hard-coded)
  const float* w_qkv  = (const float*)d_in[3];
  const float* w_proj = (const float*)d_in[4];
  const float* b_proj = (const float*)d_in[5];
  float* out = (float*)d_out;

  // workspace layout (139.6 MB total)
  char* ws = (char*)d_ws;
  float* qkv = (float*)ws;                                  // MM*D3 fp32
  f16* xh = (f16*)(ws + (size_t)MM * D3 * 4);               // MM*DD f16 (reused as attnh)
  f16* wqkvT = (f16*)(ws + (size_t)MM * D3 * 4 + (size_t)MM * DD * 2);  // D3*DD
  f16* wprojT = wqkvT + (size_t)D3 * DD;                    // DD*DD

  // prep: fp16 conversions / weight transposes
  conv_f32_to_f16<<<2048, 256, 0, stream>>>(x, xh, MM * DD / 4);
  transpose_f32_to_f16<<<dim3(D3 / 32, DD / 32), 256, 0, stream>>>(w_qkv,
                                                                   wqkvT, DD, D3);
  transpose_f32_to_f16<<<dim3(DD / 32, DD / 32), 256, 0, stream>>>(w_proj,
                                                                   wprojT, DD, DD);
  // 1) qkv = x @ w_qkv   (fp16 MFMA, fp32 out)
  gemm_f16nt<<<dim3(D3 / 128, MM / 128), 256, 0, stream>>>(xh, wqkvT, qkv, DD,
                                                           D3, nullptr);
  // 2) spatial attention + temporal mean -> fp16 (overwrites xh, now dead)
  attn_kernel<<<BB * HH * TT, 256, 0, stream>>>(qkv, xh);
  // 3) out = attn @ w_proj + b_proj
  gemm_f16nt<<<dim3(DD / 128, MM / 128), 256, 0, stream>>>(xh, wprojT, out, DD,
                                                           DD, b_proj);
}

// Round 3
// 247.475 us; speedup vs baseline: 4.2530x; 1.9407x over previous
//
#include <hip/hip_runtime.h>
#include <math.h>

// Problem constants (fixed by setup_inputs)
#define BB 8
#define TT 8
#define NN 196
#define DD 768
#define HH 12
#define HD 64
#define TN (TT * NN)   // 1568
#define MM (BB * TN)   // 12544
#define D3 (3 * DD)    // 2304

typedef _Float16 f16;
typedef _Float16 f16x8 __attribute__((ext_vector_type(8)));
typedef _Float16 f16x4 __attribute__((ext_vector_type(4)));
typedef float f32x4 __attribute__((ext_vector_type(4)));
typedef unsigned int u32;

// async global->LDS, 16B per lane; LDS dest must be wave-uniform base + lane*16
#define GLDS16(gp, lp)                                                        \
  __builtin_amdgcn_global_load_lds(                                           \
      (const __attribute__((address_space(1))) u32*)(gp),                     \
      (__attribute__((address_space(3))) u32*)(lp), 16, 0, 0)

#define MFMA16(a, b, c) __builtin_amdgcn_mfma_f32_16x16x32_f16(a, b, c, 0, 0, 0)

// ---------------------------------------------------------------------------
// fp16 NT GEMM via MFMA: C = A[M][K] @ Bt[Ncol][K]^T (+bias)
// Output either fp32 (C32) or fp16 (C16) -- exactly one non-null.
// 128x128 tile, BK=32, 256 threads (2x2 waves), 4x4 of 16x16x32 MFMA.
// ---------------------------------------------------------------------------
__global__ __launch_bounds__(256) void gemm_f16nt(
    const f16* __restrict__ A, const f16* __restrict__ Bt,
    float* __restrict__ C32, f16* __restrict__ C16, int K, int Ncol,
    const float* __restrict__ bias) {
  __shared__ f16 As[128 * 32];
  __shared__ f16 Bs[128 * 32];

  const int tid = threadIdx.x;
  const int lane = tid & 63;
  const int wave = tid >> 6;
  const int wy = wave >> 1, wx = wave & 1;
  const int bm = blockIdx.y * 128;
  const int bn = blockIdx.x * 128;

  const int ci0 = tid;
  const int ci1 = tid + 256;
  const int r0 = ci0 >> 2, c0 = ci0 & 3;
  const int r1 = ci1 >> 2, c1 = ci1 & 3;

  const f16* a0p = A + (size_t)(bm + r0) * K + c0 * 8;
  const f16* a1p = A + (size_t)(bm + r1) * K + c1 * 8;
  const f16* b0p = Bt + (size_t)(bn + r0) * K + c0 * 8;
  const f16* b1p = Bt + (size_t)(bn + r1) * K + c1 * 8;

  f32x4 acc[4][4];
#pragma unroll
  for (int i = 0; i < 4; i++)
#pragma unroll
    for (int j = 0; j < 4; j++) acc[i][j] = (f32x4)0.0f;

  const int fr = lane & 15;
  const int fq = (lane >> 4) * 8;

  for (int kt = 0; kt < K; kt += 32) {
    GLDS16(a0p + kt, &As[ci0 * 8]);
    GLDS16(a1p + kt, &As[ci1 * 8]);
    GLDS16(b0p + kt, &Bs[ci0 * 8]);
    GLDS16(b1p + kt, &Bs[ci1 * 8]);
    __syncthreads();

    f16x8 af[4], bf[4];
#pragma unroll
    for (int mi = 0; mi < 4; mi++)
      af[mi] = *(const f16x8*)&As[(wy * 64 + mi * 16 + fr) * 32 + fq];
#pragma unroll
    for (int ni = 0; ni < 4; ni++)
      bf[ni] = *(const f16x8*)&Bs[(wx * 64 + ni * 16 + fr) * 32 + fq];

#pragma unroll
    for (int mi = 0; mi < 4; mi++)
#pragma unroll
      for (int ni = 0; ni < 4; ni++)
        acc[mi][ni] = MFMA16(af[mi], bf[ni], acc[mi][ni]);

    __syncthreads();
  }

#pragma unroll
  for (int mi = 0; mi < 4; mi++) {
    const int row0 = bm + wy * 64 + mi * 16 + (lane >> 4) * 4;
#pragma unroll
    for (int ni = 0; ni < 4; ni++) {
      const int col = bn + wx * 64 + ni * 16 + (lane & 15);
      float bv = (bias != nullptr) ? bias[col] : 0.0f;
      if (C16 != nullptr) {
#pragma unroll
        for (int r = 0; r < 4; r++)
          C16[(size_t)(row0 + r) * Ncol + col] = (f16)(acc[mi][ni][r] + bv);
      } else {
#pragma unroll
        for (int r = 0; r < 4; r++)
          C32[(size_t)(row0 + r) * Ncol + col] = acc[mi][ni][r] + bv;
      }
    }
  }
}

// ---------------------------------------------------------------------------
// elementwise fp32 -> fp16
// ---------------------------------------------------------------------------
__global__ __launch_bounds__(256) void conv_f32_to_f16(
    const float* __restrict__ in, f16* __restrict__ out, int n4) {
  int i = blockIdx.x * blockDim.x + threadIdx.x;
  const int stride = gridDim.x * blockDim.x;
  for (; i < n4; i += stride) {
    float4 f = ((const float4*)in)[i];
    f16x4 h;
    h[0] = (f16)f.x;
    h[1] = (f16)f.y;
    h[2] = (f16)f.z;
    h[3] = (f16)f.w;
    ((f16x4*)out)[i] = h;
  }
}

// ---------------------------------------------------------------------------
// W[K][Ncol] fp32 -> Wt[Ncol][K] fp16
// ---------------------------------------------------------------------------
__global__ __launch_bounds__(256) void transpose_f32_to_f16(
    const float* __restrict__ W, f16* __restrict__ Wt, int K, int Ncol) {
  __shared__ float tileS[32][33];
  const int k0 = blockIdx.y * 32, n0 = blockIdx.x * 32;
  const int tx = threadIdx.x & 31, ty = threadIdx.x >> 5;
#pragma unroll
  for (int i = 0; i < 4; i++)
    tileS[ty + i * 8][tx] = W[(size_t)(k0 + ty + i * 8) * Ncol + n0 + tx];
  __syncthreads();
#pragma unroll
  for (int i = 0; i < 4; i++)
    Wt[(size_t)(n0 + ty + i * 8) * K + k0 + tx] = (f16)tileS[tx][ty + i * 8];
}

// ---------------------------------------------------------------------------
// MFMA attention per (b,h,t): S=Q.K^T, p=exp(s*scale) (scores bounded, no
// max-subtraction needed), O=P.V, plus temporal V-mean folded in.
//
// LDS: K[224 rows][64] fp16, 16B chunks XOR-swizzled by (row&7)
//      V^T[64][224] fp16 (key-contiguous rows, for PV B-frags)
//      P per-wave [16][40] fp16 (C/D->A layout round trip)
// Keys padded to 224 (zeroed, p masked); queries padded to 208 (clamped rows,
// writes guarded). Total LDS = 63744 B.
// ---------------------------------------------------------------------------
#define KP 224
#define VSTR 224

__global__ __launch_bounds__(256) void attn_mfma(
    const f16* __restrict__ qkv, f16* __restrict__ out) {
  __shared__ f16 KS[KP * 64];
  __shared__ f16 VS[64 * VSTR];
  __shared__ f16 PS[4 * 16 * 40];
  __shared__ float red[256];
  __shared__ float vmean[64];

  const int bi = blockIdx.x;  // b*H*T + h*T + t
  const int t = bi % TT;
  const int h = (bi / TT) % HH;
  const int b = bi / (TT * HH);
  const int tok0 = b * TN + t * NN;

  const int tid = threadIdx.x;
  const int lane = tid & 63;
  const int wave = tid >> 6;
  const int m = lane & 15;
  const int q = lane >> 4;

  // ---- stage K (swizzled rows), zero pad rows 196..223 ----
#pragma unroll
  for (int it = 0; it < 7; it++) {
    int idx = tid + it * 256;
    int key = idx >> 3, c = idx & 7;
    f16x8 val = {0, 0, 0, 0, 0, 0, 0, 0};
    if (key < NN)
      val = *(const f16x8*)(qkv + (size_t)(tok0 + key) * D3 + DD + h * HD +
                            c * 8);
    *(f16x8*)&KS[key * 64 + ((c ^ (key & 7)) * 8)] = val;
  }

  // ---- stage V^T (transpose via register gather) + v-mean partials ----
  const int vd = tid & 63;
  const int kb = tid >> 6;
  float vpart = 0.0f;
#pragma unroll
  for (int it = 0; it < 7; it++) {
    int k0 = kb * 56 + it * 8;
    f16x8 pk;
#pragma unroll
    for (int j = 0; j < 8; j++) {
      int key = k0 + j;
      f16 v = (f16)0.0f;
      if (key < NN)
        v = qkv[(size_t)(tok0 + key) * D3 + 2 * DD + h * HD + vd];
      pk[j] = v;
      vpart += (float)v;
    }
    *(f16x8*)&VS[vd * VSTR + k0] = pk;
  }
  red[tid] = vpart;
  __syncthreads();
  if (tid < 64)
    vmean[tid] = (red[tid] + red[tid + 64] + red[tid + 128] + red[tid + 192]) *
                 (1.0f / (float)NN);
  __syncthreads();

  // ---- per-wave: query tiles round-robin (13 tiles of 16) ----
  f16* PSw = &PS[wave * 16 * 40];
  const int sw = m & 7;

  for (int qt = wave; qt < 13; qt += 4) {
    const int q0 = qt * 16;
    int qrow = q0 + m;
    if (qrow > NN - 1) qrow = NN - 1;  // clamp padded queries
    const f16* qbase = qkv + (size_t)(tok0 + qrow) * D3 + h * HD;
    f16x8 aq0 = *(const f16x8*)(qbase + q * 8);
    f16x8 aq1 = *(const f16x8*)(qbase + 32 + q * 8);

    f32x4 o0 = (f32x4)0.0f, o1 = (f32x4)0.0f, o2 = (f32x4)0.0f,
          o3 = (f32x4)0.0f;
    float l[4] = {0.0f, 0.0f, 0.0f, 0.0f};

    for (int ch = 0; ch < 7; ch++) {
      const int keyA = ch * 32 + m;
      const int keyB = keyA + 16;
      f16x8 b00 = *(const f16x8*)&KS[keyA * 64 + ((q ^ sw) * 8)];
      f16x8 b01 = *(const f16x8*)&KS[keyA * 64 + (((q + 4) ^ sw) * 8)];
      f16x8 b10 = *(const f16x8*)&KS[keyB * 64 + ((q ^ sw) * 8)];
      f16x8 b11 = *(const f16x8*)&KS[keyB * 64 + (((q + 4) ^ sw) * 8)];
      f32x4 z = (f32x4)0.0f;
      f32x4 s0 = MFMA16(aq0, b00, z);
      s0 = MFMA16(aq1, b01, s0);
      f32x4 s1 = MFMA16(aq0, b10, z);
      s1 = MFMA16(aq1, b11, s1);

      const bool v0 = (ch < 6) || (m < 4);  // key < 196 masks
      const bool v1 = (ch < 6);
#pragma unroll
      for (int r = 0; r < 4; r++) {
        float p0 = v0 ? __expf(s0[r] * 0.125f) : 0.0f;
        float p1 = v1 ? __expf(s1[r] * 0.125f) : 0.0f;
        l[r] += p0 + p1;
        PSw[(q * 4 + r) * 40 + m] = (f16)p0;
        PSw[(q * 4 + r) * 40 + 16 + m] = (f16)p1;
      }
      f16x8 pa = *(const f16x8*)&PSw[m * 40 + q * 8];
      f16x8 bv0 = *(const f16x8*)&VS[(0 * 16 + m) * VSTR + ch * 32 + q * 8];
      f16x8 bv1 = *(const f16x8*)&VS[(1 * 16 + m) * VSTR + ch * 32 + q * 8];
      f16x8 bv2 = *(const f16x8*)&VS[(2 * 16 + m) * VSTR + ch * 32 + q * 8];
      f16x8 bv3 = *(const f16x8*)&VS[(3 * 16 + m) * VSTR + ch * 32 + q * 8];
      o0 = MFMA16(pa, bv0, o0);
      o1 = MFMA16(pa, bv1, o1);
      o2 = MFMA16(pa, bv2, o2);
      o3 = MFMA16(pa, bv3, o3);
    }

    // row-sum l across the 16 lanes holding each row's columns
#pragma unroll
    for (int r = 0; r < 4; r++) {
      float s = l[r];
      s += __shfl_xor(s, 1);
      s += __shfl_xor(s, 2);
      s += __shfl_xor(s, 4);
      s += __shfl_xor(s, 8);
      l[r] = 1.0f / s;
    }

    // write O: row=q0+q*4+r, col=dt*16+m
#pragma unroll
    for (int r = 0; r < 4; r++) {
      const int query = q0 + q * 4 + r;
      if (query < NN) {
        f16* orow = out + (size_t)(tok0 + query) * DD + h * HD;
        orow[m] = (f16)(o0[r] * l[r] + vmean[m]);
        orow[16 + m] = (f16)(o1[r] * l[r] + vmean[16 + m]);
        orow[32 + m] = (f16)(o2[r] * l[r] + vmean[32 + m]);
        orow[48 + m] = (f16)(o3[r] * l[r] + vmean[48 + m]);
      }
    }
  }
}

// ---------------------------------------------------------------------------
extern "C" void kernel_launch(void* const* d_in, const int* in_sizes, int n_in,
                              void* d_out, int out_size, void* d_ws,
                              size_t ws_size, hipStream_t stream) {
  (void)in_sizes;
  (void)n_in;
  (void)out_size;
  (void)ws_size;
  const float* x      = (const float*)d_in[0];
  const float* w_qkv  = (const float*)d_in[3];
  const float* w_proj = (const float*)d_in[4];
  const float* b_proj = (const float*)d_in[5];
  float* out = (float*)d_out;

  // workspace: qkvh (fp16 MM*D3) | xh (fp16 MM*DD, reused for attn out) |
  //            wqkvT | wprojT    (~82 MB total)
  char* ws = (char*)d_ws;
  f16* qkvh = (f16*)ws;
  f16* xh = (f16*)(ws + (size_t)MM * D3 * 2);
  f16* wqkvT = xh + (size_t)MM * DD;
  f16* wprojT = wqkvT + (size_t)D3 * DD;

  conv_f32_to_f16<<<2048, 256, 0, stream>>>(x, xh, MM * DD / 4);
  transpose_f32_to_f16<<<dim3(D3 / 32, DD / 32), 256, 0, stream>>>(w_qkv,
                                                                   wqkvT, DD, D3);
  transpose_f32_to_f16<<<dim3(DD / 32, DD / 32), 256, 0, stream>>>(w_proj,
                                                                   wprojT, DD, DD);
  // 1) qkv (fp16) = x @ w_qkv
  gemm_f16nt<<<dim3(D3 / 128, MM / 128), 256, 0, stream>>>(
      xh, wqkvT, nullptr, qkvh, DD, D3, nullptr);
  // 2) MFMA attention + temporal mean -> fp16 (overwrites xh)
  attn_mfma<<<BB * HH * TT, 256, 0, stream>>>(qkvh, xh);
  // 3) out = attn @ w_proj + b_proj (fp32 out)
  gemm_f16nt<<<dim3(DD / 128, MM / 128), 256, 0, stream>>>(
      xh, wprojT, out, nullptr, DD, DD, b_proj);
}

// Round 4
// 239.497 us; speedup vs baseline: 4.3947x; 1.0333x over previous
//
#include <hip/hip_runtime.h>
#include <math.h>

// Problem constants (fixed by setup_inputs)
#define BB 8
#define TT 8
#define NN 196
#define DD 768
#define HH 12
#define HD 64
#define TN (TT * NN)   // 1568
#define MM (BB * TN)   // 12544
#define D3 (3 * DD)    // 2304

typedef _Float16 f16;
typedef _Float16 f16x8 __attribute__((ext_vector_type(8)));
typedef _Float16 f16x4 __attribute__((ext_vector_type(4)));
typedef float f32x4 __attribute__((ext_vector_type(4)));
typedef unsigned int u32;

// async global->LDS, 16B per lane; LDS dest must be wave-uniform base + lane*16
#define GLDS16(gp, lp)                                                        \
  __builtin_amdgcn_global_load_lds(                                           \
      (const __attribute__((address_space(1))) u32*)(gp),                     \
      (__attribute__((address_space(3))) u32*)(lp), 16, 0, 0)

#define MFMA16(a, b, c) __builtin_amdgcn_mfma_f32_16x16x32_f16(a, b, c, 0, 0, 0)

// ---------------------------------------------------------------------------
// fp16 NT GEMM via MFMA: C = A[M][K] @ Bt[Ncol][K]^T (+bias)
// Output either fp32 (C32) or fp16 (C16) -- exactly one non-null.
// 128x128 tile, BK=32, 256 threads (2x2 waves), 4x4 of 16x16x32 MFMA.
// LDS chunk-XOR swizzle by (row>>1)&3 -> fragment b128 reads are 2-way (free).
// Swizzle is absorbed into the global source address of global_load_lds.
// ---------------------------------------------------------------------------
__global__ __launch_bounds__(256) void gemm_f16nt(
    const f16* __restrict__ A, const f16* __restrict__ Bt,
    float* __restrict__ C32, f16* __restrict__ C16, int K, int Ncol,
    const float* __restrict__ bias) {
  __shared__ f16 As[128 * 32];
  __shared__ f16 Bs[128 * 32];

  const int tid = threadIdx.x;
  const int lane = tid & 63;
  const int wave = tid >> 6;
  const int wy = wave >> 1, wx = wave & 1;
  const int bm = blockIdx.y * 128;
  const int bn = blockIdx.x * 128;

  // staging: physical chunk ci -> global logical chunk (ci&3) ^ ((row>>1)&3)
  const int ci0 = tid;
  const int ci1 = tid + 256;
  const int r0 = ci0 >> 2, c0 = (ci0 & 3) ^ ((r0 >> 1) & 3);
  const int r1 = ci1 >> 2, c1 = (ci1 & 3) ^ ((r1 >> 1) & 3);

  const f16* a0p = A + (size_t)(bm + r0) * K + c0 * 8;
  const f16* a1p = A + (size_t)(bm + r1) * K + c1 * 8;
  const f16* b0p = Bt + (size_t)(bn + r0) * K + c0 * 8;
  const f16* b1p = Bt + (size_t)(bn + r1) * K + c1 * 8;

  f32x4 acc[4][4];
#pragma unroll
  for (int i = 0; i < 4; i++)
#pragma unroll
    for (int j = 0; j < 4; j++) acc[i][j] = (f32x4)0.0f;

  // fragment read: row*32 + ((q ^ ((row>>1)&3)) * 8) halves
  const int fr = lane & 15;
  const int fqp = (((lane >> 4) ^ ((fr >> 1) & 3)) * 8);

  for (int kt = 0; kt < K; kt += 32) {
    GLDS16(a0p + kt, &As[ci0 * 8]);
    GLDS16(a1p + kt, &As[ci1 * 8]);
    GLDS16(b0p + kt, &Bs[ci0 * 8]);
    GLDS16(b1p + kt, &Bs[ci1 * 8]);
    __syncthreads();

    f16x8 af[4], bf[4];
#pragma unroll
    for (int mi = 0; mi < 4; mi++)
      af[mi] = *(const f16x8*)&As[(wy * 64 + mi * 16 + fr) * 32 + fqp];
#pragma unroll
    for (int ni = 0; ni < 4; ni++)
      bf[ni] = *(const f16x8*)&Bs[(wx * 64 + ni * 16 + fr) * 32 + fqp];

#pragma unroll
    for (int mi = 0; mi < 4; mi++)
#pragma unroll
      for (int ni = 0; ni < 4; ni++)
        acc[mi][ni] = MFMA16(af[mi], bf[ni], acc[mi][ni]);

    __syncthreads();
  }

#pragma unroll
  for (int mi = 0; mi < 4; mi++) {
    const int row0 = bm + wy * 64 + mi * 16 + (lane >> 4) * 4;
#pragma unroll
    for (int ni = 0; ni < 4; ni++) {
      const int col = bn + wx * 64 + ni * 16 + (lane & 15);
      float bv = (bias != nullptr) ? bias[col] : 0.0f;
      if (C16 != nullptr) {
#pragma unroll
        for (int r = 0; r < 4; r++)
          C16[(size_t)(row0 + r) * Ncol + col] = (f16)(acc[mi][ni][r] + bv);
      } else {
#pragma unroll
        for (int r = 0; r < 4; r++)
          C32[(size_t)(row0 + r) * Ncol + col] = acc[mi][ni][r] + bv;
      }
    }
  }
}

// ---------------------------------------------------------------------------
// elementwise fp32 -> fp16
// ---------------------------------------------------------------------------
__global__ __launch_bounds__(256) void conv_f32_to_f16(
    const float* __restrict__ in, f16* __restrict__ out, int n4) {
  int i = blockIdx.x * blockDim.x + threadIdx.x;
  const int stride = gridDim.x * blockDim.x;
  for (; i < n4; i += stride) {
    float4 f = ((const float4*)in)[i];
    f16x4 h;
    h[0] = (f16)f.x;
    h[1] = (f16)f.y;
    h[2] = (f16)f.z;
    h[3] = (f16)f.w;
    ((f16x4*)out)[i] = h;
  }
}

// ---------------------------------------------------------------------------
// W[K][Ncol] fp32 -> Wt[Ncol][K] fp16
// ---------------------------------------------------------------------------
__global__ __launch_bounds__(256) void transpose_f32_to_f16(
    const float* __restrict__ W, f16* __restrict__ Wt, int K, int Ncol) {
  __shared__ float tileS[32][33];
  const int k0 = blockIdx.y * 32, n0 = blockIdx.x * 32;
  const int tx = threadIdx.x & 31, ty = threadIdx.x >> 5;
#pragma unroll
  for (int i = 0; i < 4; i++)
    tileS[ty + i * 8][tx] = W[(size_t)(k0 + ty + i * 8) * Ncol + n0 + tx];
  __syncthreads();
#pragma unroll
  for (int i = 0; i < 4; i++)
    Wt[(size_t)(n0 + ty + i * 8) * K + k0 + tx] = (f16)tileS[tx][ty + i * 8];
}

// ---------------------------------------------------------------------------
// MFMA attention per (b,h,t), 512 threads (8 waves) for latency hiding.
// S=Q.K^T, p=exp(s*scale) (bounded scores, no max-subtraction), O=P.V,
// temporal V-mean folded in.
//
// LDS (65,280 B; 2 blocks/CU):
//   KS[196][64] f16, 16B chunks XOR-swizzled by (key&7); padded key reads
//     CLAMPED to row 195 (scores junk-free, p already masked for key>=196)
//   VS = V^T[64][232] f16 (stride 232 halves = 464 B -> 2-way banks, free);
//     cols 196..231 zeroed
//   PS per-wave [16][40] f16 (C/D->A layout round trip); overlaps red[]
// ---------------------------------------------------------------------------
#define VSTR 232

__global__ __launch_bounds__(512, 4) void attn_mfma(
    const f16* __restrict__ qkv, f16* __restrict__ out) {
  __shared__ f16 KS[196 * 64];
  __shared__ f16 VS[64 * VSTR];
  __shared__ __align__(16) f16 PS[8 * 16 * 40];
  __shared__ float vmean[64];
  float* red = (float*)PS;  // red used strictly before PS (barrier between)

  const int bi = blockIdx.x;  // b*H*T + h*T + t
  const int t = bi % TT;
  const int h = (bi / TT) % HH;
  const int b = bi / (TT * HH);
  const int tok0 = b * TN + t * NN;

  const int tid = threadIdx.x;
  const int lane = tid & 63;
  const int wave = tid >> 6;  // 0..7
  const int m = lane & 15;
  const int q = lane >> 4;

  // ---- stage K (swizzled chunks), rows 0..195 only ----
#pragma unroll
  for (int it = 0; it < 4; it++) {
    int idx = tid + it * 512;
    if (idx < 196 * 8) {
      int key = idx >> 3, c = idx & 7;
      f16x8 val = *(const f16x8*)(qkv + (size_t)(tok0 + key) * D3 + DD +
                                  h * HD + c * 8);
      *(f16x8*)&KS[key * 64 + ((c ^ (key & 7)) * 8)] = val;
    }
  }

  // ---- zero VS pad cols [196,232) ----
  for (int idx = tid; idx < 64 * 9; idx += 512) {
    int d = idx / 9, c = idx % 9;
    *(f16x4*)&VS[d * VSTR + 196 + c * 4] = (f16x4){0, 0, 0, 0};
  }

  // ---- stage V^T (register-gather transpose) + v-mean partials ----
  const int vd = tid & 63;
  const int kb = tid >> 6;  // 0..7; kb==7 idle (7*28 = 196 keys exactly)
  float vpart = 0.0f;
  if (kb < 7) {
#pragma unroll
    for (int it = 0; it < 7; it++) {
      int k0 = kb * 28 + it * 4;
      f16x4 pk;
#pragma unroll
      for (int j = 0; j < 4; j++) {
        f16 v = qkv[(size_t)(tok0 + k0 + j) * D3 + 2 * DD + h * HD + vd];
        pk[j] = v;
        vpart += (float)v;
      }
      *(f16x4*)&VS[vd * VSTR + k0] = pk;
    }
  }
  red[tid] = vpart;
  __syncthreads();
  if (tid < 64) {
    float s = 0.0f;
#pragma unroll
    for (int g = 0; g < 8; g++) s += red[tid + 64 * g];
    vmean[tid] = s * (1.0f / (float)NN);
  }
  __syncthreads();  // red dead; PS region free for reuse

  // ---- per-wave: query tiles round-robin (13 tiles of 16 over 8 waves) ----
  f16* PSw = &PS[wave * 640];

  for (int qt = wave; qt < 13; qt += 8) {
    const int q0 = qt * 16;
    int qrow = q0 + m;
    if (qrow > NN - 1) qrow = NN - 1;  // clamp padded queries (write-guarded)
    const f16* qbase = qkv + (size_t)(tok0 + qrow) * D3 + h * HD;
    f16x8 aq0 = *(const f16x8*)(qbase + q * 8);
    f16x8 aq1 = *(const f16x8*)(qbase + 32 + q * 8);

    f32x4 o0 = (f32x4)0.0f, o1 = (f32x4)0.0f, o2 = (f32x4)0.0f,
          o3 = (f32x4)0.0f;
    float l[4] = {0.0f, 0.0f, 0.0f, 0.0f};

    for (int ch = 0; ch < 7; ch++) {
      const int keyA = ch * 32 + m;
      const int keyB = keyA + 16;
      const int kA = keyA > 195 ? 195 : keyA;
      const int kB = keyB > 195 ? 195 : keyB;
      const int swA = kA & 7, swB = kB & 7;
      f16x8 b00 = *(const f16x8*)&KS[kA * 64 + ((q ^ swA) * 8)];
      f16x8 b01 = *(const f16x8*)&KS[kA * 64 + (((q + 4) ^ swA) * 8)];
      f16x8 b10 = *(const f16x8*)&KS[kB * 64 + ((q ^ swB) * 8)];
      f16x8 b11 = *(const f16x8*)&KS[kB * 64 + (((q + 4) ^ swB) * 8)];
      f32x4 z = (f32x4)0.0f;
      f32x4 s0 = MFMA16(aq0, b00, z);
      s0 = MFMA16(aq1, b01, s0);
      f32x4 s1 = MFMA16(aq0, b10, z);
      s1 = MFMA16(aq1, b11, s1);

      const bool v0 = keyA < NN;
      const bool v1 = keyB < NN;
#pragma unroll
      for (int r = 0; r < 4; r++) {
        float p0 = v0 ? __expf(s0[r] * 0.125f) : 0.0f;
        float p1 = v1 ? __expf(s1[r] * 0.125f) : 0.0f;
        l[r] += p0 + p1;
        PSw[(q * 4 + r) * 40 + m] = (f16)p0;
        PSw[(q * 4 + r) * 40 + 16 + m] = (f16)p1;
      }
      f16x8 pa = *(const f16x8*)&PSw[m * 40 + q * 8];
      f16x8 bv0 = *(const f16x8*)&VS[(0 * 16 + m) * VSTR + ch * 32 + q * 8];
      f16x8 bv1 = *(const f16x8*)&VS[(1 * 16 + m) * VSTR + ch * 32 + q * 8];
      f16x8 bv2 = *(const f16x8*)&VS[(2 * 16 + m) * VSTR + ch * 32 + q * 8];
      f16x8 bv3 = *(const f16x8*)&VS[(3 * 16 + m) * VSTR + ch * 32 + q * 8];
      o0 = MFMA16(pa, bv0, o0);
      o1 = MFMA16(pa, bv1, o1);
      o2 = MFMA16(pa, bv2, o2);
      o3 = MFMA16(pa, bv3, o3);
    }

    // row-sum l across the 16 lanes holding each row's columns
#pragma unroll
    for (int r = 0; r < 4; r++) {
      float s = l[r];
      s += __shfl_xor(s, 1);
      s += __shfl_xor(s, 2);
      s += __shfl_xor(s, 4);
      s += __shfl_xor(s, 8);
      l[r] = 1.0f / s;
    }

    // write O: row=q0+q*4+r, col=g*16+m
#pragma unroll
    for (int r = 0; r < 4; r++) {
      const int query = q0 + q * 4 + r;
      if (query < NN) {
        f16* orow = out + (size_t)(tok0 + query) * DD + h * HD;
        orow[m] = (f16)(o0[r] * l[r] + vmean[m]);
        orow[16 + m] = (f16)(o1[r] * l[r] + vmean[16 + m]);
        orow[32 + m] = (f16)(o2[r] * l[r] + vmean[32 + m]);
        orow[48 + m] = (f16)(o3[r] * l[r] + vmean[48 + m]);
      }
    }
  }
}

// ---------------------------------------------------------------------------
extern "C" void kernel_launch(void* const* d_in, const int* in_sizes, int n_in,
                              void* d_out, int out_size, void* d_ws,
                              size_t ws_size, hipStream_t stream) {
  (void)in_sizes;
  (void)n_in;
  (void)out_size;
  (void)ws_size;
  const float* x      = (const float*)d_in[0];
  const float* w_qkv  = (const float*)d_in[3];
  const float* w_proj = (const float*)d_in[4];
  const float* b_proj = (const float*)d_in[5];
  float* out = (float*)d_out;

  // workspace: qkvh (fp16 MM*D3) | xh (fp16 MM*DD, reused for attn out) |
  //            wqkvT | wprojT    (~82 MB total)
  char* ws = (char*)d_ws;
  f16* qkvh = (f16*)ws;
  f16* xh = (f16*)(ws + (size_t)MM * D3 * 2);
  f16* wqkvT = xh + (size_t)MM * DD;
  f16* wprojT = wqkvT + (size_t)D3 * DD;

  conv_f32_to_f16<<<2048, 256, 0, stream>>>(x, xh, MM * DD / 4);
  transpose_f32_to_f16<<<dim3(D3 / 32, DD / 32), 256, 0, stream>>>(w_qkv,
                                                                   wqkvT, DD, D3);
  transpose_f32_to_f16<<<dim3(DD / 32, DD / 32), 256, 0, stream>>>(w_proj,
                                                                   wprojT, DD, DD);
  // 1) qkv (fp16) = x @ w_qkv
  gemm_f16nt<<<dim3(D3 / 128, MM / 128), 256, 0, stream>>>(
      xh, wqkvT, nullptr, qkvh, DD, D3, nullptr);
  // 2) MFMA attention + temporal mean -> fp16 (overwrites xh)
  attn_mfma<<<BB * HH * TT, 512, 0, stream>>>(qkvh, xh);
  // 3) out = attn @ w_proj + b_proj (fp32 out)
  gemm_f16nt<<<dim3(DD / 128, MM / 128), 256, 0, stream>>>(
      xh, wprojT, out, nullptr, DD, DD, b_proj);
}

// Round 5
// 234.144 us; speedup vs baseline: 4.4951x; 1.0229x over previous
//
#include <hip/hip_runtime.h>
#include <math.h>

// Problem constants (fixed by setup_inputs)
#define BB 8
#define TT 8
#define NN 196
#define DD 768
#define HH 12
#define HD 64
#define TN (TT * NN)   // 1568
#define MM (BB * TN)   // 12544
#define D3 (3 * DD)    // 2304

typedef _Float16 f16;
typedef _Float16 f16x8 __attribute__((ext_vector_type(8)));
typedef _Float16 f16x4 __attribute__((ext_vector_type(4)));
typedef float f32x4 __attribute__((ext_vector_type(4)));
typedef unsigned int u32;

// async global->LDS, 16B per lane; LDS dest must be wave-uniform base + lane*16
#define GLDS16(gp, lp)                                                        \
  __builtin_amdgcn_global_load_lds(                                           \
      (const __attribute__((address_space(1))) u32*)(gp),                     \
      (__attribute__((address_space(3))) u32*)(lp), 16, 0, 0)

#define MFMA16(a, b, c) __builtin_amdgcn_mfma_f32_16x16x32_f16(a, b, c, 0, 0, 0)

// ---------------------------------------------------------------------------
// fp16 NT GEMM via MFMA: C = A[M][K] @ Bt[Ncol][K]^T
// mode 0: fp32 out + bias (token-major)           -> C32
// mode 1: fp16 out scattered to qkv tile layout   -> C16
//         dest[(frame*HH+h)*3 + qt][n][d], frame=token/196, n=token%196,
//         qt=col/768, h=(col%768)/64, d=col%64
// 128x128 tile, BK=64, 256 threads (2x2 waves), 2x(4x4) of 16x16x32 MFMA.
// LDS chunk-XOR swizzle by (row&7); swizzle absorbed into global src address.
// ---------------------------------------------------------------------------
__global__ __launch_bounds__(256) void gemm_f16nt(
    const f16* __restrict__ A, const f16* __restrict__ Bt,
    float* __restrict__ C32, f16* __restrict__ C16, int K, int Ncol,
    const float* __restrict__ bias, int mode) {
  __shared__ f16 As[128 * 64];
  __shared__ f16 Bs[128 * 64];

  const int tid = threadIdx.x;
  const int lane = tid & 63;
  const int wave = tid >> 6;
  const int wy = wave >> 1, wx = wave & 1;
  const int bm = blockIdx.y * 128;
  const int bn = blockIdx.x * 128;

  // staging: 1024 chunks (16B) per matrix; 4 per thread.
  // physical chunk ci -> row=ci>>3, logical chunk c=(ci&7)^(row&7)
  const f16* aP[4];
  const f16* bP[4];
#pragma unroll
  for (int it = 0; it < 4; it++) {
    int ci = tid + it * 256;
    int r = ci >> 3;
    int c = (ci & 7) ^ (r & 7);
    aP[it] = A + (size_t)(bm + r) * K + c * 8;
    bP[it] = Bt + (size_t)(bn + r) * K + c * 8;
  }

  f32x4 acc[4][4];
#pragma unroll
  for (int i = 0; i < 4; i++)
#pragma unroll
    for (int j = 0; j < 4; j++) acc[i][j] = (f32x4)0.0f;

  const int fr = lane & 15;
  const int q = lane >> 4;
  const int sw = fr & 7;

  for (int kt = 0; kt < K; kt += 64) {
#pragma unroll
    for (int it = 0; it < 4; it++) {
      GLDS16(aP[it] + kt, &As[(tid + it * 256) * 8]);
      GLDS16(bP[it] + kt, &Bs[(tid + it * 256) * 8]);
    }
    __syncthreads();

#pragma unroll
    for (int kk = 0; kk < 2; kk++) {
      const int lc = ((kk * 4 + q) ^ sw) * 8;
      f16x8 af[4], bf[4];
#pragma unroll
      for (int mi = 0; mi < 4; mi++)
        af[mi] = *(const f16x8*)&As[(wy * 64 + mi * 16 + fr) * 64 + lc];
#pragma unroll
      for (int ni = 0; ni < 4; ni++)
        bf[ni] = *(const f16x8*)&Bs[(wx * 64 + ni * 16 + fr) * 64 + lc];

#pragma unroll
      for (int mi = 0; mi < 4; mi++)
#pragma unroll
        for (int ni = 0; ni < 4; ni++)
          acc[mi][ni] = MFMA16(af[mi], bf[ni], acc[mi][ni]);
    }
    __syncthreads();
  }

  if (mode == 0) {
#pragma unroll
    for (int mi = 0; mi < 4; mi++) {
      const int row0 = bm + wy * 64 + mi * 16 + (lane >> 4) * 4;
#pragma unroll
      for (int ni = 0; ni < 4; ni++) {
        const int col = bn + wx * 64 + ni * 16 + (lane & 15);
        float bv = (bias != nullptr) ? bias[col] : 0.0f;
#pragma unroll
        for (int r = 0; r < 4; r++)
          C32[(size_t)(row0 + r) * Ncol + col] = acc[mi][ni][r] + bv;
      }
    }
  } else {
    // qkv scatter epilogue
#pragma unroll
    for (int mi = 0; mi < 4; mi++) {
      const int row0 = bm + wy * 64 + mi * 16 + (lane >> 4) * 4;
#pragma unroll
      for (int r = 0; r < 4; r++) {
        const int token = row0 + r;
        const int f = token / NN;
        const int n = token - f * NN;
        f16* fb = C16 + ((size_t)f * (HH * 3) * NN) * 64 + n * 64;
#pragma unroll
        for (int ni = 0; ni < 4; ni++) {
          const int col = bn + wx * 64 + ni * 16 + (lane & 15);
          const int qt = col / DD;
          const int rem = col - qt * DD;
          const int hh = rem >> 6;
          const int d = rem & 63;
          fb[(size_t)(hh * 3 + qt) * NN * 64 + d] = (f16)acc[mi][ni][r];
        }
      }
    }
  }
}

// ---------------------------------------------------------------------------
// elementwise fp32 -> fp16
// ---------------------------------------------------------------------------
__global__ __launch_bounds__(256) void conv_f32_to_f16(
    const float* __restrict__ in, f16* __restrict__ out, int n4) {
  int i = blockIdx.x * blockDim.x + threadIdx.x;
  const int stride = gridDim.x * blockDim.x;
  for (; i < n4; i += stride) {
    float4 f = ((const float4*)in)[i];
    f16x4 h;
    h[0] = (f16)f.x;
    h[1] = (f16)f.y;
    h[2] = (f16)f.z;
    h[3] = (f16)f.w;
    ((f16x4*)out)[i] = h;
  }
}

// ---------------------------------------------------------------------------
// W[K][Ncol] fp32 -> Wt[Ncol][K] fp16
// ---------------------------------------------------------------------------
__global__ __launch_bounds__(256) void transpose_f32_to_f16(
    const float* __restrict__ W, f16* __restrict__ Wt, int K, int Ncol) {
  __shared__ float tileS[32][33];
  const int k0 = blockIdx.y * 32, n0 = blockIdx.x * 32;
  const int tx = threadIdx.x & 31, ty = threadIdx.x >> 5;
#pragma unroll
  for (int i = 0; i < 4; i++)
    tileS[ty + i * 8][tx] = W[(size_t)(k0 + ty + i * 8) * Ncol + n0 + tx];
  __syncthreads();
#pragma unroll
  for (int i = 0; i < 4; i++)
    Wt[(size_t)(n0 + ty + i * 8) * K + k0 + tx] = (f16)tileS[tx][ty + i * 8];
}

// ---------------------------------------------------------------------------
// MFMA attention per (b,h,t), 512 threads (8 waves).
// qkv input layout: per (frame,h): [3][196][64] contiguous tiles.
// S=Q.K^T, p=exp(s*scale) (bounded scores, no max-subtraction), O=P.V,
// temporal V-mean folded in. Output token-major fp16 [token][768].
//
// LDS (65,280 B; 2 blocks/CU):
//   KS[196][64] f16, 16B chunks XOR-swizzled by (key&7), staged via
//     global_load_lds; padded key reads CLAMPED to row 195 (p masked)
//   VS = V^T[64][232] f16 (stride 464 B -> 2-way banks, free)
//   PS per-wave [16][40] f16 (C/D->A layout round trip); overlaps red[]
// ---------------------------------------------------------------------------
#define VSTR 232

__global__ __launch_bounds__(512, 4) void attn_mfma(
    const f16* __restrict__ qkv, f16* __restrict__ out) {
  __shared__ f16 KS[196 * 64];
  __shared__ f16 VS[64 * VSTR];
  __shared__ __align__(16) f16 PS[8 * 16 * 40];
  __shared__ float vmean[64];
  float* red = (float*)PS;  // red used strictly before PS (barrier between)

  const int bi = blockIdx.x;  // b*H*T + h*T + t
  const int t = bi % TT;
  const int h = (bi / TT) % HH;
  const int b = bi / (TT * HH);
  const int frame = b * TT + t;
  const int tok0 = frame * NN;

  const f16* Qb = qkv + (size_t)(frame * HH + h) * 3 * NN * 64;
  const f16* Kb = Qb + NN * 64;
  const f16* Vb = Qb + 2 * NN * 64;

  const int tid = threadIdx.x;
  const int lane = tid & 63;
  const int wave = tid >> 6;  // 0..7
  const int m = lane & 15;
  const int q = lane >> 4;

  // ---- stage K via global_load_lds (swizzled source), 1568 chunks ----
#pragma unroll
  for (int it = 0; it < 3; it++) {
    int chunk = tid + it * 512;
    int row = chunk >> 3, pc = chunk & 7;
    int c = pc ^ (row & 7);
    GLDS16(Kb + row * 64 + c * 8, &KS[chunk * 8]);
  }
  if (tid < 32) {  // remainder 32 chunks (rows 192..195), regular path
    int chunk = 1536 + tid;
    int row = chunk >> 3, pc = chunk & 7;
    int c = pc ^ (row & 7);
    *(f16x8*)&KS[chunk * 8] = *(const f16x8*)(Kb + row * 64 + c * 8);
  }

  // ---- zero VS pad cols [196,232) ----
  for (int idx = tid; idx < 64 * 9; idx += 512) {
    int d = idx / 9, c = idx % 9;
    *(f16x4*)&VS[d * VSTR + 196 + c * 4] = (f16x4){0, 0, 0, 0};
  }

  // ---- stage V^T (register-gather transpose) + v-mean partials ----
  const int vd = tid & 63;
  const int kb = tid >> 6;  // 0..7; kb==7 idle (7*28 = 196 keys exactly)
  float vpart = 0.0f;
  if (kb < 7) {
#pragma unroll
    for (int it = 0; it < 7; it++) {
      int k0 = kb * 28 + it * 4;
      f16x4 pk;
#pragma unroll
      for (int j = 0; j < 4; j++) {
        f16 v = Vb[(k0 + j) * 64 + vd];
        pk[j] = v;
        vpart += (float)v;
      }
      *(f16x4*)&VS[vd * VSTR + k0] = pk;
    }
  }
  red[tid] = vpart;
  __syncthreads();
  if (tid < 64) {
    float s = 0.0f;
#pragma unroll
    for (int g = 0; g < 8; g++) s += red[tid + 64 * g];
    vmean[tid] = s * (1.0f / (float)NN);
  }
  __syncthreads();  // red dead; PS region free for reuse

  // ---- per-wave: query tiles round-robin (13 tiles of 16 over 8 waves) ----
  f16* PSw = &PS[wave * 640];

  for (int qt = wave; qt < 13; qt += 8) {
    const int q0 = qt * 16;
    int qrow = q0 + m;
    if (qrow > NN - 1) qrow = NN - 1;  // clamp padded queries (write-guarded)
    const f16* qbase = Qb + qrow * 64;
    f16x8 aq0 = *(const f16x8*)(qbase + q * 8);
    f16x8 aq1 = *(const f16x8*)(qbase + 32 + q * 8);

    f32x4 o0 = (f32x4)0.0f, o1 = (f32x4)0.0f, o2 = (f32x4)0.0f,
          o3 = (f32x4)0.0f;
    float l[4] = {0.0f, 0.0f, 0.0f, 0.0f};

    for (int ch = 0; ch < 7; ch++) {
      const int keyA = ch * 32 + m;
      const int keyB = keyA + 16;
      const int kA = keyA > 195 ? 195 : keyA;
      const int kB = keyB > 195 ? 195 : keyB;
      const int swA = kA & 7, swB = kB & 7;
      f16x8 b00 = *(const f16x8*)&KS[kA * 64 + ((q ^ swA) * 8)];
      f16x8 b01 = *(const f16x8*)&KS[kA * 64 + (((q + 4) ^ swA) * 8)];
      f16x8 b10 = *(const f16x8*)&KS[kB * 64 + ((q ^ swB) * 8)];
      f16x8 b11 = *(const f16x8*)&KS[kB * 64 + (((q + 4) ^ swB) * 8)];
      f32x4 z = (f32x4)0.0f;
      f32x4 s0 = MFMA16(aq0, b00, z);
      s0 = MFMA16(aq1, b01, s0);
      f32x4 s1 = MFMA16(aq0, b10, z);
      s1 = MFMA16(aq1, b11, s1);

      const bool v0 = keyA < NN;
      const bool v1 = keyB < NN;
#pragma unroll
      for (int r = 0; r < 4; r++) {
        float p0 = v0 ? __expf(s0[r] * 0.125f) : 0.0f;
        float p1 = v1 ? __expf(s1[r] * 0.125f) : 0.0f;
        l[r] += p0 + p1;
        PSw[(q * 4 + r) * 40 + m] = (f16)p0;
        PSw[(q * 4 + r) * 40 + 16 + m] = (f16)p1;
      }
      f16x8 pa = *(const f16x8*)&PSw[m * 40 + q * 8];
      f16x8 bv0 = *(const f16x8*)&VS[(0 * 16 + m) * VSTR + ch * 32 + q * 8];
      f16x8 bv1 = *(const f16x8*)&VS[(1 * 16 + m) * VSTR + ch * 32 + q * 8];
      f16x8 bv2 = *(const f16x8*)&VS[(2 * 16 + m) * VSTR + ch * 32 + q * 8];
      f16x8 bv3 = *(const f16x8*)&VS[(3 * 16 + m) * VSTR + ch * 32 + q * 8];
      o0 = MFMA16(pa, bv0, o0);
      o1 = MFMA16(pa, bv1, o1);
      o2 = MFMA16(pa, bv2, o2);
      o3 = MFMA16(pa, bv3, o3);
    }

    // row-sum l across the 16 lanes holding each row's columns
#pragma unroll
    for (int r = 0; r < 4; r++) {
      float s = l[r];
      s += __shfl_xor(s, 1);
      s += __shfl_xor(s, 2);
      s += __shfl_xor(s, 4);
      s += __shfl_xor(s, 8);
      l[r] = 1.0f / s;
    }

    // write O: row=q0+q*4+r (token-major), col=g*16+m
#pragma unroll
    for (int r = 0; r < 4; r++) {
      const int query = q0 + q * 4 + r;
      if (query < NN) {
        f16* orow = out + (size_t)(tok0 + query) * DD + h * HD;
        orow[m] = (f16)(o0[r] * l[r] + vmean[m]);
        orow[16 + m] = (f16)(o1[r] * l[r] + vmean[16 + m]);
        orow[32 + m] = (f16)(o2[r] * l[r] + vmean[32 + m]);
        orow[48 + m] = (f16)(o3[r] * l[r] + vmean[48 + m]);
      }
    }
  }
}

// ---------------------------------------------------------------------------
extern "C" void kernel_launch(void* const* d_in, const int* in_sizes, int n_in,
                              void* d_out, int out_size, void* d_ws,
                              size_t ws_size, hipStream_t stream) {
  (void)in_sizes;
  (void)n_in;
  (void)out_size;
  (void)ws_size;
  const float* x      = (const float*)d_in[0];
  const float* w_qkv  = (const float*)d_in[3];
  const float* w_proj = (const float*)d_in[4];
  const float* b_proj = (const float*)d_in[5];
  float* out = (float*)d_out;

  // workspace: qkvh (fp16 MM*D3, tile layout) | xh (fp16 MM*DD, reused for
  //            attn out) | wqkvT | wprojT   (~82 MB total)
  char* ws = (char*)d_ws;
  f16* qkvh = (f16*)ws;
  f16* xh = (f16*)(ws + (size_t)MM * D3 * 2);
  f16* wqkvT = xh + (size_t)MM * DD;
  f16* wprojT = wqkvT + (size_t)D3 * DD;

  conv_f32_to_f16<<<2048, 256, 0, stream>>>(x, xh, MM * DD / 4);
  transpose_f32_to_f16<<<dim3(D3 / 32, DD / 32), 256, 0, stream>>>(w_qkv,
                                                                   wqkvT, DD, D3);
  transpose_f32_to_f16<<<dim3(DD / 32, DD / 32), 256, 0, stream>>>(w_proj,
                                                                   wprojT, DD, DD);
  // 1) qkv (fp16, attention tile layout) = x @ w_qkv
  gemm_f16nt<<<dim3(D3 / 128, MM / 128), 256, 0, stream>>>(
      xh, wqkvT, nullptr, qkvh, DD, D3, nullptr, 1);
  // 2) MFMA attention + temporal mean -> fp16 token-major (overwrites xh)
  attn_mfma<<<BB * HH * TT, 512, 0, stream>>>(qkvh, xh);
  // 3) out = attn @ w_proj + b_proj (fp32 out)
  gemm_f16nt<<<dim3(DD / 128, MM / 128), 256, 0, stream>>>(
      xh, wprojT, out, nullptr, DD, DD, b_proj, 0);
}